// Round 3
// baseline (1708.335 us; speedup 1.0000x reference)
//
#include <hip/hip_runtime.h>
#include <stdint.h>

#define N1     97
#define N1SQ   9409
#define NV3    912673      // 97^3 lattice vertices
#define RES    96
#define NCELL  884736      // 96^3 cells
#define NCOLS  9409        // 97*97 z-columns
#define NBLK1  4705        // ceil(NCOLS/2): phase-1 blocks (2 columns each)
#define SEG    19          // NBLK1 <= 256*SEG
#define UVFLOATS 42467328  // 2304^2*8

#define VB2 3566           // ceil(NV3/256)
#define FB2 3456           // NCELL/256
#define NSPARSE (VB2 + FB2)                        // 7022
#define UVB2 10368                                 // uvs blocks (1024 float4 each)
#define P2BLOCKS (2 * NSPARSE + (UVB2 - NSPARSE))  // 17390
#define GRID_TOTAL (NBLK1 + P2BLOCKS)              // 22095

typedef float f4v __attribute__((ext_vector_type(4)));

__device__ __constant__ int d_tt[16][6] = {
    {-1,-1,-1,-1,-1,-1}, {1,0,2,-1,-1,-1}, {4,0,3,-1,-1,-1}, {1,4,2,1,3,4},
    {3,1,5,-1,-1,-1}, {2,3,0,2,5,3}, {1,4,0,1,5,4}, {4,2,5,-1,-1,-1},
    {4,5,2,-1,-1,-1}, {4,1,0,4,5,1}, {3,2,0,3,5,2}, {1,3,5,-1,-1,-1},
    {4,1,2,4,3,1}, {3,0,4,-1,-1,-1}, {2,0,1,-1,-1,-1}, {-1,-1,-1,-1,-1,-1}};
__device__ __constant__ int d_six[6][4] = {
    {0,5,1,7},{0,1,3,7},{0,3,2,7},{0,2,6,7},{0,6,4,7},{0,4,5,7}};
__device__ __constant__ int d_eb[6][2] = {{0,1},{0,2},{0,3},{1,2},{1,3},{2,3}};

__device__ __forceinline__ int corner_off(int b) {
    return (b >> 2) * N1SQ + ((b >> 1) & 1) * N1 + (b & 1);
}

__device__ __forceinline__ float uvval(uint32_t p) {
    uint32_t cell = p >> 3;
    uint32_t k = p & 7u;
    uint32_t i = cell / 2304u;
    uint32_t j = cell - i * 2304u;
    uint32_t idx = (k & 1u) ? i : j;
    bool addpad = (k & 1u) ? (k >= 5u) : (k == 2u || k == 4u);
    return (float)idx * (1.0f / 2304.0f) + (addpad ? 0.9f / 2304.0f : 0.0f);
}

__device__ __forceinline__ f4v uvval4(uint32_t p) {  // p % 4 == 0
    uint32_t cell = p >> 3;
    uint32_t i = cell / 2304u;
    uint32_t j = cell - i * 2304u;
    const float s = 1.0f / 2304.0f, pd = 0.9f / 2304.0f;
    float xx = (float)j * s, yy = (float)i * s;
    f4v v;
    if (p & 4u) { v.x = xx + pd; v.y = yy + pd; v.z = xx;      v.w = yy + pd; }
    else        { v.x = xx;      v.y = yy;      v.z = xx + pd; v.w = yy; }
    return v;
}

// ctl layout: [0]=ticket [1]=done [2]=flagTot [3]=flagScan [4]=accNV [5]=accM1 [6]=accM2
__global__ __launch_bounds__(256) void k_mega(
    const float* __restrict__ sdf, const float* __restrict__ pos,
    uint32_t* __restrict__ ctl, uint32_t* __restrict__ tot,
    uint8_t* __restrict__ mask, uint16_t* __restrict__ vloc,
    uint32_t* __restrict__ vsums, uint8_t* __restrict__ cocc,
    uint32_t* __restrict__ cloc, uint64_t* __restrict__ csums,
    float* __restrict__ out) {
    __shared__ uint32_t s_ticket;
    __shared__ uint32_t s_last;
    __shared__ uint8_t  sgn[2][128];
    __shared__ uint32_t wtv[4];
    __shared__ uint64_t wtc[4];

    int t = threadIdx.x;
    int lane = t & 63, wv = t >> 6;
    if (t == 0)
        s_ticket = __hip_atomic_fetch_add(&ctl[0], 1u, __ATOMIC_RELAXED, __HIP_MEMORY_SCOPE_AGENT);
    __syncthreads();
    uint32_t ticket = s_ticket;

    if (ticket < NBLK1) {
        // ---------------- phase 1: 2 z-columns per block ----------------
        int half = t >> 7, z = t & 127;
        int col = (int)ticket * 2 + half;
        bool vcol = col < NCOLS;
        int x = 0, y = 0;
        if (vcol) { x = col / N1; y = col - x * N1; }
        bool bx = x < RES, by = y < RES, bz = z < RES;
        bool vact = vcol && (z < N1);
        int b00 = col * N1;
        float f00 = 0.f, f01 = 0.f, f10 = 0.f, f11 = 0.f;
        if (vact) {
            f00 = sdf[b00 + z];
            if (by) f01 = sdf[b00 + N1 + z];
            if (bx) f10 = sdf[b00 + N1SQ + z];
            if (bx && by) f11 = sdf[b00 + N1SQ + N1 + z];
        }
        uint32_t sb = (f00 >= 0.f ? 1u : 0u) | (f01 >= 0.f ? 2u : 0u) |
                      (f10 >= 0.f ? 4u : 0u) | (f11 >= 0.f ? 8u : 0u);
        sgn[half][z] = (uint8_t)sb;
        __syncthreads();
        uint32_t s1 = bz ? (uint32_t)sgn[half][z + 1] : 0u;

        uint32_t o0 = sb & 1u;
        uint32_t vm = 0;
        if (vact) {
            if (bz && ((s1 & 1u) != o0)) vm |= 1u;
            if (by && (((sb >> 1) & 1u) != o0)) vm |= 2u;
            if (by && bz && (((s1 >> 1) & 1u) != o0)) vm |= 4u;
            if (bx && (((sb >> 2) & 1u) != o0)) vm |= 8u;
            if (bx && bz && (((s1 >> 2) & 1u) != o0)) vm |= 16u;
            if (bx && by && (((sb >> 3) & 1u) != o0)) vm |= 32u;
            if (bx && by && bz && (((s1 >> 3) & 1u) != o0)) vm |= 64u;
        }
        uint32_t cnt = __popc(vm);
        bool cact = vact && bx && by && bz;
        uint32_t occ = 0, m1 = 0, m2 = 0;
        if (cact) {
            occ = (sb & 1u) | ((s1 & 1u) << 1) | (((sb >> 1) & 1u) << 2) | (((s1 >> 1) & 1u) << 3) |
                  (((sb >> 2) & 1u) << 4) | (((s1 >> 2) & 1u) << 5) |
                  (((sb >> 3) & 1u) << 6) | (((s1 >> 3) & 1u) << 7);
            if (occ != 0u && occ != 255u) {
#pragma unroll
                for (int k = 0; k < 6; k++) {
                    int ti = ((occ >> d_six[k][0]) & 1) | (((occ >> d_six[k][1]) & 1) << 1) |
                             (((occ >> d_six[k][2]) & 1) << 2) | (((occ >> d_six[k][3]) & 1) << 3);
                    int pc = __popc((uint32_t)ti);
                    m1 += (pc == 1 || pc == 3) ? 1u : 0u;
                    m2 += (pc == 2) ? 1u : 0u;
                }
            }
        }
        // packed u64 scan: cnt[0:16) | m1[16:32) | m2[32:..)
        uint64_t val = (uint64_t)(cnt | (m1 << 16)) | ((uint64_t)m2 << 32);
        unsigned long long incl = val;
#pragma unroll
        for (int d = 1; d < 64; d <<= 1) {
            unsigned long long u = __shfl_up(incl, d, 64);
            if (lane >= d) incl += u;
        }
        if (lane == 63) wtc[wv] = incl;
        __syncthreads();
        uint64_t pre = 0;
#pragma unroll
        for (int w = 0; w < 4; w++)
            if (w < wv) pre += wtc[w];
        uint64_t excl = pre + (uint64_t)incl - val;
        uint64_t btot = wtc[0] + wtc[1] + wtc[2] + wtc[3];

        if (vact) {
            mask[b00 + z] = (uint8_t)vm;
            vloc[b00 + z] = (uint16_t)(excl & 0xffffu);
        }
        if (cact) {
            int c = (x * RES + y) * RES + z;
            cocc[c] = (uint8_t)occ;
            cloc[c] = (uint32_t)((excl >> 16) & 0xffffu) | ((uint32_t)((excl >> 32) & 0xffffu) << 16);
        }
        if (t == 0) {
            vsums[ticket] = (uint32_t)(btot & 0xffffu);
            csums[ticket] = ((btot >> 16) & 0xffffu) | (((btot >> 32) & 0xffffu) << 32);
        }
        __syncthreads();  // drain all global stores (barrier waits vmcnt(0))
        if (t == 0) {
            __hip_atomic_fetch_add(&ctl[4], (uint32_t)(btot & 0xffffu), __ATOMIC_RELAXED, __HIP_MEMORY_SCOPE_AGENT);
            __hip_atomic_fetch_add(&ctl[5], (uint32_t)((btot >> 16) & 0xffffu), __ATOMIC_RELAXED, __HIP_MEMORY_SCOPE_AGENT);
            __hip_atomic_fetch_add(&ctl[6], (uint32_t)((btot >> 32) & 0xffffu), __ATOMIC_RELAXED, __HIP_MEMORY_SCOPE_AGENT);
            uint32_t d = __hip_atomic_fetch_add(&ctl[1], 1u, __ATOMIC_ACQ_REL, __HIP_MEMORY_SCOPE_AGENT);
            s_last = (d == NBLK1 - 1) ? 1u : 0u;
        }
        __syncthreads();
        if (!s_last) return;

        // ---------------- closer: totals + block-prefix scan ----------------
        if (t == 0) {
            uint32_t NV  = __hip_atomic_load(&ctl[4], __ATOMIC_RELAXED, __HIP_MEMORY_SCOPE_AGENT);
            uint32_t NF1 = __hip_atomic_load(&ctl[5], __ATOMIC_RELAXED, __HIP_MEMORY_SCOPE_AGENT);
            uint32_t NF2 = __hip_atomic_load(&ctl[6], __ATOMIC_RELAXED, __HIP_MEMORY_SCOPE_AGENT);
            uint32_t NF = NF1 + 2u * NF2;
            tot[0] = NV; tot[1] = NF1; tot[2] = NF2;
            tot[3] = NV * 6u;
            tot[4] = NV * 6u + NF * 3u;
            tot[5] = NV * 6u + NF * 3u + UVFLOATS;
            __hip_atomic_store(&ctl[2], 1u, __ATOMIC_RELEASE, __HIP_MEMORY_SCOPE_AGENT);  // uvs may go
        }
        uint32_t sv = 0; uint64_t sc = 0;
        int base = t * SEG;
#pragma unroll 1
        for (int j = 0; j < SEG; j++) {
            int idx = base + j;
            if (idx < NBLK1) { sv += vsums[idx]; sc += csums[idx]; }
        }
        uint32_t iv = sv; unsigned long long ic = sc;
#pragma unroll
        for (int d = 1; d < 64; d <<= 1) {
            uint32_t u1 = __shfl_up(iv, d, 64);
            unsigned long long u2 = __shfl_up(ic, d, 64);
            if (lane >= d) { iv += u1; ic += u2; }
        }
        if (lane == 63) { wtv[wv] = iv; wtc[wv] = ic; }
        __syncthreads();
        uint32_t pv = 0; uint64_t pc2 = 0;
#pragma unroll
        for (int w = 0; w < 4; w++)
            if (w < wv) { pv += wtv[w]; pc2 += wtc[w]; }
        uint32_t rv = pv + iv - sv;
        uint64_t rc = pc2 + (uint64_t)ic - sc;
#pragma unroll 1
        for (int j = 0; j < SEG; j++) {
            int idx = base + j;
            if (idx < NBLK1) {
                uint32_t a = vsums[idx]; uint64_t b = csums[idx];
                vsums[idx] = rv; csums[idx] = rc;
                rv += a; rc += b;
            }
        }
        __syncthreads();  // drain prefix writes
        if (t == 0)
            __hip_atomic_store(&ctl[3], 1u, __ATOMIC_RELEASE, __HIP_MEMORY_SCOPE_AGENT);
        return;
    }

    // ---------------- phase 2 ----------------
    uint32_t r = ticket - NBLK1;
    int sparse = -1, uvb = -1;
    if (r < 2u * NSPARSE) {
        if (r & 1u) uvb = (int)(r >> 1);
        else sparse = (int)(r >> 1);
    } else {
        uvb = NSPARSE + (int)(r - 2u * NSPARSE);
    }

    if (uvb >= 0) {
        if (t == 0) {
            while (__hip_atomic_load(&ctl[2], __ATOMIC_RELAXED, __HIP_MEMORY_SCOPE_AGENT) == 0u)
                __builtin_amdgcn_s_sleep(32);
            (void)__hip_atomic_load(&ctl[2], __ATOMIC_ACQUIRE, __HIP_MEMORY_SCOPE_AGENT);
        }
        __syncthreads();
        uint32_t tot4 = tot[4];
        uint32_t A = (tot4 + 3u) & ~3u;
        uint32_t end = tot4 + UVFLOATS;
        uint32_t nvec = (end - A) >> 2;
#pragma unroll
        for (int rr = 0; rr < 4; rr++) {
            uint32_t vi = (uint32_t)uvb * 1024u + (uint32_t)rr * 256u + (uint32_t)t;
            if (vi < nvec) {
                uint32_t e = A + vi * 4u;
                f4v val = uvval4(e - tot4);
                __builtin_nontemporal_store(val, (f4v*)(out + e));
            }
        }
        if (uvb == 0 && t == 0) {
            for (uint32_t e = tot4; e < A; e++) out[e] = uvval(e - tot4);
            for (uint32_t e = A + nvec * 4u; e < end; e++) out[e] = uvval(e - tot4);
        }
        return;
    }

    // sparse roles wait for the full prefix scan
    if (t == 0) {
        while (__hip_atomic_load(&ctl[3], __ATOMIC_RELAXED, __HIP_MEMORY_SCOPE_AGENT) == 0u)
            __builtin_amdgcn_s_sleep(32);
        (void)__hip_atomic_load(&ctl[3], __ATOMIC_ACQUIRE, __HIP_MEMORY_SCOPE_AGENT);
    }
    __syncthreads();

    if (sparse < VB2) {
        // ---- verts ----
        int v = sparse * 256 + t;
        if (v >= NV3) return;
        uint32_t m = mask[v];
        if (!m) return;
        uint32_t vid = (uint32_t)vloc[v] + vsums[(v / N1) >> 1];
        float sa = sdf[v];
        const float* pa = pos + (size_t)v * 6;
        const int diroff[7] = {1, 97, 98, 9409, 9410, 9506, 9507};
#pragma unroll
        for (int d = 0; d < 7; d++) {
            if (!((m >> d) & 1)) continue;
            int b = v + diroff[d];
            float sbv = sdf[b];
            float denom = sa - sbv;
            float w0 = -sbv / denom;
            float w1 = sa / denom;
            const float* pb = pos + (size_t)b * 6;
            float* o = out + (size_t)vid * 6;
#pragma unroll
            for (int k = 0; k < 6; k++) o[k] = pa[k] * w0 + pb[k] * w1;
            vid++;
        }
        return;
    }

    // ---- faces + uv_idx ----
    {
        int c = (sparse - VB2) * 256 + t;  // FB2*256 == NCELL
        uint32_t occ = cocc[c];
        if (occ == 0u || occ == 255u) return;
        int cx = c / (RES * RES);
        int rr0 = c - cx * (RES * RES);
        int cy = rr0 / RES;
        int cz = rr0 - cy * RES;
        int base = cx * N1SQ + cy * N1 + cz;
        int blkc = (cx * N1 + cy) >> 1;
        uint32_t cl = cloc[c];
        uint64_t cs = csums[blkc];
        uint32_t r1 = (uint32_t)(cs & 0xffffffffu) + (cl & 0xffffu);
        uint32_t r2 = (uint32_t)(cs >> 32) + (cl >> 16);
        uint32_t NF1 = tot[1];
        uint32_t fbase = tot[3];
        uint32_t ubase = tot[5];
#pragma unroll 1
        for (int k = 0; k < 6; k++) {
            int ti = ((occ >> d_six[k][0]) & 1) | (((occ >> d_six[k][1]) & 1) << 1) |
                     (((occ >> d_six[k][2]) & 1) << 2) | (((occ >> d_six[k][3]) & 1) << 3);
            int pc = __popc((uint32_t)ti);
            int nt = (pc == 2) ? 2 : ((pc == 1 || pc == 3) ? 1 : 0);
            if (!nt) continue;
            uint32_t t_g = (uint32_t)c * 6u + (uint32_t)k;
            uint32_t row0;
            if (nt == 1) { row0 = r1; r1++; }
            else         { row0 = NF1 + 2u * r2; r2++; }
            for (int tri = 0; tri < nt; tri++) {
                uint32_t rr = row0 + (uint32_t)tri;
                float* f = out + (size_t)fbase + (size_t)rr * 3;
                float* u = out + (size_t)ubase + (size_t)rr * 3;
#pragma unroll
                for (int j = 0; j < 3; j++) {
                    int e = d_tt[ti][tri * 3 + j];
                    int c0 = d_six[k][d_eb[e][0]];
                    int c1 = d_six[k][d_eb[e][1]];
                    int bl = c0 & c1;
                    int rank = (c0 ^ c1) - 1;
                    int v0 = base + corner_off(bl);
                    uint32_t vid = (uint32_t)vloc[v0] + vsums[(v0 / N1) >> 1] +
                                   (uint32_t)__popc((uint32_t)mask[v0] & ((1u << rank) - 1u));
                    f[j] = (float)vid;
                }
                u[0] = (float)(4u * t_g);
                u[1] = (float)(4u * t_g + (uint32_t)tri + 1u);
                u[2] = (float)(4u * t_g + (uint32_t)tri + 2u);
            }
        }
    }
}

extern "C" void kernel_launch(void* const* d_in, const int* in_sizes, int n_in,
                              void* d_out, int out_size, void* d_ws, size_t ws_size,
                              hipStream_t stream) {
    const float* pos = (const float*)d_in[0];
    const float* sdf = (const float*)d_in[1];
    float* out = (float*)d_out;

    uint8_t* ws = (uint8_t*)d_ws;
    size_t off = 0;
    auto alloc = [&](size_t bytes) {
        void* p = ws + off;
        off = (off + bytes + 255) & ~(size_t)255;
        return p;
    };
    uint32_t* ctl   = (uint32_t*)alloc(64);          // MUST be at ws offset 0 (memset target)
    uint32_t* tot   = (uint32_t*)alloc(64);
    uint8_t*  mask  = (uint8_t*)alloc(NV3);
    uint16_t* vloc  = (uint16_t*)alloc((size_t)NV3 * 2);
    uint32_t* vsums = (uint32_t*)alloc((size_t)NBLK1 * 4);
    uint8_t*  cocc  = (uint8_t*)alloc(NCELL);
    uint32_t* cloc  = (uint32_t*)alloc((size_t)NCELL * 4);
    uint64_t* csums = (uint64_t*)alloc((size_t)NBLK1 * 8);

    hipMemsetAsync(ctl, 0, 64, stream);
    hipLaunchKernelGGL(k_mega, dim3(GRID_TOTAL), dim3(256), 0, stream,
                       sdf, pos, ctl, tot, mask, vloc, vsums, cocc, cloc, csums, out);
}

// Round 4
// 97.399 us; speedup vs baseline: 17.5396x; 17.5396x over previous
//
#include <hip/hip_runtime.h>
#include <stdint.h>

#define N1     97
#define N1SQ   9409
#define NV3    912673      // 97^3 lattice vertices
#define RES    96
#define NCELL  884736      // 96^3 cells
#define NCOLS  9409        // 97*97 z-columns
#define NBLK1  4705        // ceil(NCOLS/2): phase-1 blocks (2 columns each)
#define SEG    19          // NBLK1 <= 256*SEG
#define UVFLOATS 42467328  // 2304^2*8

#define VB2 3566           // ceil(NV3/256)
#define FB2 3456           // NCELL/256
#define NSPARSE (VB2 + FB2)                        // 7022
#define UVB2 10368                                 // uvs blocks (1024 float4 each)
#define P2BLOCKS (2 * NSPARSE + (UVB2 - NSPARSE))  // 17390

typedef float f4v __attribute__((ext_vector_type(4)));

__device__ __constant__ int d_tt[16][6] = {
    {-1,-1,-1,-1,-1,-1}, {1,0,2,-1,-1,-1}, {4,0,3,-1,-1,-1}, {1,4,2,1,3,4},
    {3,1,5,-1,-1,-1}, {2,3,0,2,5,3}, {1,4,0,1,5,4}, {4,2,5,-1,-1,-1},
    {4,5,2,-1,-1,-1}, {4,1,0,4,5,1}, {3,2,0,3,5,2}, {1,3,5,-1,-1,-1},
    {4,1,2,4,3,1}, {3,0,4,-1,-1,-1}, {2,0,1,-1,-1,-1}, {-1,-1,-1,-1,-1,-1}};
__device__ __constant__ int d_six[6][4] = {
    {0,5,1,7},{0,1,3,7},{0,3,2,7},{0,2,6,7},{0,6,4,7},{0,4,5,7}};
__device__ __constant__ int d_eb[6][2] = {{0,1},{0,2},{0,3},{1,2},{1,3},{2,3}};

__device__ __forceinline__ int corner_off(int b) {
    return (b >> 2) * N1SQ + ((b >> 1) & 1) * N1 + (b & 1);
}

__device__ __forceinline__ float uvval(uint32_t p) {
    uint32_t cell = p >> 3;
    uint32_t k = p & 7u;
    uint32_t i = cell / 2304u;
    uint32_t j = cell - i * 2304u;
    uint32_t idx = (k & 1u) ? i : j;
    bool addpad = (k & 1u) ? (k >= 5u) : (k == 2u || k == 4u);
    return (float)idx * (1.0f / 2304.0f) + (addpad ? 0.9f / 2304.0f : 0.0f);
}

__device__ __forceinline__ f4v uvval4(uint32_t p) {  // p % 4 == 0
    uint32_t cell = p >> 3;
    uint32_t i = cell / 2304u;
    uint32_t j = cell - i * 2304u;
    const float s = 1.0f / 2304.0f, pd = 0.9f / 2304.0f;
    float xx = (float)j * s, yy = (float)i * s;
    f4v v;
    if (p & 4u) { v.x = xx + pd; v.y = yy + pd; v.z = xx;      v.w = yy + pd; }
    else        { v.x = xx;      v.y = yy;      v.z = xx + pd; v.w = yy; }
    return v;
}

// Phase 1: 2 z-columns per block; coalesced loads; vertex mask + cell occ from
// the same 4 loads via LDS sign table; packed u64 wave scan (1 barrier).
__global__ __launch_bounds__(256) void k_p1(const float* __restrict__ sdf,
                                            uint8_t* __restrict__ mask,
                                            uint16_t* __restrict__ vloc,
                                            uint32_t* __restrict__ vsums,
                                            uint8_t* __restrict__ cocc,
                                            uint32_t* __restrict__ cloc,
                                            uint64_t* __restrict__ csums) {
    __shared__ uint8_t  sgn[2][128];
    __shared__ uint64_t wtc[4];
    int t = threadIdx.x;
    int lane = t & 63, wv = t >> 6;
    int bid = blockIdx.x;
    int half = t >> 7, z = t & 127;
    int col = bid * 2 + half;
    bool vcol = col < NCOLS;
    int x = 0, y = 0;
    if (vcol) { x = col / N1; y = col - x * N1; }
    bool bx = x < RES, by = y < RES, bz = z < RES;
    bool vact = vcol && (z < N1);
    int b00 = col * N1;
    float f00 = 0.f, f01 = 0.f, f10 = 0.f, f11 = 0.f;
    if (vact) {
        f00 = sdf[b00 + z];
        if (by) f01 = sdf[b00 + N1 + z];
        if (bx) f10 = sdf[b00 + N1SQ + z];
        if (bx && by) f11 = sdf[b00 + N1SQ + N1 + z];
    }
    uint32_t sb = (f00 >= 0.f ? 1u : 0u) | (f01 >= 0.f ? 2u : 0u) |
                  (f10 >= 0.f ? 4u : 0u) | (f11 >= 0.f ? 8u : 0u);
    sgn[half][z] = (uint8_t)sb;
    __syncthreads();
    uint32_t s1 = bz ? (uint32_t)sgn[half][z + 1] : 0u;

    uint32_t o0 = sb & 1u;
    uint32_t vm = 0;
    if (vact) {
        if (bz && ((s1 & 1u) != o0)) vm |= 1u;
        if (by && (((sb >> 1) & 1u) != o0)) vm |= 2u;
        if (by && bz && (((s1 >> 1) & 1u) != o0)) vm |= 4u;
        if (bx && (((sb >> 2) & 1u) != o0)) vm |= 8u;
        if (bx && bz && (((s1 >> 2) & 1u) != o0)) vm |= 16u;
        if (bx && by && (((sb >> 3) & 1u) != o0)) vm |= 32u;
        if (bx && by && bz && (((s1 >> 3) & 1u) != o0)) vm |= 64u;
    }
    uint32_t cnt = __popc(vm);
    bool cact = vact && bx && by && bz;
    uint32_t occ = 0, m1 = 0, m2 = 0;
    if (cact) {
        occ = (sb & 1u) | ((s1 & 1u) << 1) | (((sb >> 1) & 1u) << 2) | (((s1 >> 1) & 1u) << 3) |
              (((sb >> 2) & 1u) << 4) | (((s1 >> 2) & 1u) << 5) |
              (((sb >> 3) & 1u) << 6) | (((s1 >> 3) & 1u) << 7);
        if (occ != 0u && occ != 255u) {
#pragma unroll
            for (int k = 0; k < 6; k++) {
                int ti = ((occ >> d_six[k][0]) & 1) | (((occ >> d_six[k][1]) & 1) << 1) |
                         (((occ >> d_six[k][2]) & 1) << 2) | (((occ >> d_six[k][3]) & 1) << 3);
                int pc = __popc((uint32_t)ti);
                m1 += (pc == 1 || pc == 3) ? 1u : 0u;
                m2 += (pc == 2) ? 1u : 0u;
            }
        }
    }
    // packed u64 scan: cnt[0:16) | m1[16:32) | m2[32:..)
    uint64_t val = (uint64_t)(cnt | (m1 << 16)) | ((uint64_t)m2 << 32);
    unsigned long long incl = val;
#pragma unroll
    for (int d = 1; d < 64; d <<= 1) {
        unsigned long long u = __shfl_up(incl, d, 64);
        if (lane >= d) incl += u;
    }
    if (lane == 63) wtc[wv] = incl;
    __syncthreads();
    uint64_t pre = 0;
#pragma unroll
    for (int w = 0; w < 4; w++)
        if (w < wv) pre += wtc[w];
    uint64_t excl = pre + (uint64_t)incl - val;
    uint64_t btot = wtc[0] + wtc[1] + wtc[2] + wtc[3];

    if (vact) {
        mask[b00 + z] = (uint8_t)vm;
        vloc[b00 + z] = (uint16_t)(excl & 0xffffu);
    }
    if (cact) {
        int c = (x * RES + y) * RES + z;
        cocc[c] = (uint8_t)occ;
        cloc[c] = (uint32_t)((excl >> 16) & 0xffffu) | ((uint32_t)((excl >> 32) & 0xffffu) << 16);
    }
    if (t == 0) {
        vsums[bid] = (uint32_t)(btot & 0xffffu);
        csums[bid] = ((btot >> 16) & 0xffffu) | (((btot >> 32) & 0xffffu) << 32);
    }
}

// Sums: one block, segmented scan of the 4705 block sums + totals/offsets.
__global__ __launch_bounds__(256) void k_sums2(uint32_t* __restrict__ vsums,
                                               uint64_t* __restrict__ csums,
                                               uint32_t* __restrict__ tot) {
    __shared__ uint32_t wtv[4];
    __shared__ uint64_t wtc[4];
    int t = threadIdx.x;
    int lane = t & 63, wv = t >> 6;
    uint32_t sv = 0; uint64_t sc = 0;
    int base = t * SEG;
#pragma unroll 1
    for (int j = 0; j < SEG; j++) {
        int idx = base + j;
        if (idx < NBLK1) { sv += vsums[idx]; sc += csums[idx]; }
    }
    uint32_t iv = sv; unsigned long long ic = sc;
#pragma unroll
    for (int d = 1; d < 64; d <<= 1) {
        uint32_t u1 = __shfl_up(iv, d, 64);
        unsigned long long u2 = __shfl_up(ic, d, 64);
        if (lane >= d) { iv += u1; ic += u2; }
    }
    if (lane == 63) { wtv[wv] = iv; wtc[wv] = ic; }
    __syncthreads();
    uint32_t pv = 0; uint64_t pc2 = 0;
#pragma unroll
    for (int w = 0; w < 4; w++)
        if (w < wv) { pv += wtv[w]; pc2 += wtc[w]; }
    uint32_t rv = pv + iv - sv;
    uint64_t rc = pc2 + (uint64_t)ic - sc;
#pragma unroll 1
    for (int j = 0; j < SEG; j++) {
        int idx = base + j;
        if (idx < NBLK1) {
            uint32_t a = vsums[idx]; uint64_t b = csums[idx];
            vsums[idx] = rv; csums[idx] = rc;
            rv += a; rc += b;
        }
    }
    if (t == 0) {
        uint32_t NV  = wtv[0] + wtv[1] + wtv[2] + wtv[3];
        uint64_t tc  = wtc[0] + wtc[1] + wtc[2] + wtc[3];
        uint32_t NF1 = (uint32_t)(tc & 0xffffffffu);
        uint32_t NF2 = (uint32_t)(tc >> 32);
        uint32_t NF  = NF1 + 2u * NF2;
        tot[0] = NV; tot[1] = NF1; tot[2] = NF2;
        tot[3] = NV * 6u;
        tot[4] = NV * 6u + NF * 3u;
        tot[5] = NV * 6u + NF * 3u + UVFLOATS;
    }
}

// Phase 2 fused: interleaved roles; uvs writes (BW-bound, nontemporal) overlap
// the latency-bound verts/faces emission.
__global__ __launch_bounds__(256) void k_p2(const float* __restrict__ sdf,
                                            const float* __restrict__ pos,
                                            const uint8_t* __restrict__ mask,
                                            const uint16_t* __restrict__ vloc,
                                            const uint32_t* __restrict__ vsums,
                                            const uint8_t* __restrict__ cocc,
                                            const uint32_t* __restrict__ cloc,
                                            const uint64_t* __restrict__ csums,
                                            const uint32_t* __restrict__ tot,
                                            float* __restrict__ out) {
    int bid = blockIdx.x;
    int t = threadIdx.x;
    int sparse = -1, uvb = -1;
    if (bid < 2 * NSPARSE) {
        if (bid & 1) uvb = bid >> 1;
        else sparse = bid >> 1;
    } else {
        uvb = NSPARSE + (bid - 2 * NSPARSE);
    }

    if (uvb >= 0) {
        uint32_t tot4 = tot[4];
        uint32_t A = (tot4 + 3u) & ~3u;
        uint32_t end = tot4 + UVFLOATS;
        uint32_t nvec = (end - A) >> 2;
#pragma unroll
        for (int rr = 0; rr < 4; rr++) {
            uint32_t vi = (uint32_t)uvb * 1024u + (uint32_t)rr * 256u + (uint32_t)t;
            if (vi < nvec) {
                uint32_t e = A + vi * 4u;
                f4v val = uvval4(e - tot4);
                __builtin_nontemporal_store(val, (f4v*)(out + e));
            }
        }
        if (uvb == 0 && t == 0) {
            for (uint32_t e = tot4; e < A; e++) out[e] = uvval(e - tot4);
            for (uint32_t e = A + nvec * 4u; e < end; e++) out[e] = uvval(e - tot4);
        }
        return;
    }

    if (sparse < VB2) {
        // ---- verts ----
        int v = sparse * 256 + t;
        if (v >= NV3) return;
        uint32_t m = mask[v];
        if (!m) return;
        uint32_t vid = (uint32_t)vloc[v] + vsums[(v / N1) >> 1];
        float sa = sdf[v];
        const float* pa = pos + (size_t)v * 6;
        const int diroff[7] = {1, 97, 98, 9409, 9410, 9506, 9507};
#pragma unroll
        for (int d = 0; d < 7; d++) {
            if (!((m >> d) & 1)) continue;
            int b = v + diroff[d];
            float sbv = sdf[b];
            float denom = sa - sbv;
            float w0 = -sbv / denom;
            float w1 = sa / denom;
            const float* pb = pos + (size_t)b * 6;
            float* o = out + (size_t)vid * 6;
#pragma unroll
            for (int k = 0; k < 6; k++) o[k] = pa[k] * w0 + pb[k] * w1;
            vid++;
        }
        return;
    }

    // ---- faces + uv_idx ----
    {
        int c = (sparse - VB2) * 256 + t;  // FB2*256 == NCELL
        uint32_t occ = cocc[c];
        if (occ == 0u || occ == 255u) return;
        int cx = c / (RES * RES);
        int rr0 = c - cx * (RES * RES);
        int cy = rr0 / RES;
        int cz = rr0 - cy * RES;
        int base = cx * N1SQ + cy * N1 + cz;
        int blkc = (cx * N1 + cy) >> 1;
        uint32_t cl = cloc[c];
        uint64_t cs = csums[blkc];
        uint32_t r1 = (uint32_t)(cs & 0xffffffffu) + (cl & 0xffffu);
        uint32_t r2 = (uint32_t)(cs >> 32) + (cl >> 16);
        uint32_t NF1 = tot[1];
        uint32_t fbase = tot[3];
        uint32_t ubase = tot[5];
#pragma unroll 1
        for (int k = 0; k < 6; k++) {
            int ti = ((occ >> d_six[k][0]) & 1) | (((occ >> d_six[k][1]) & 1) << 1) |
                     (((occ >> d_six[k][2]) & 1) << 2) | (((occ >> d_six[k][3]) & 1) << 3);
            int pc = __popc((uint32_t)ti);
            int nt = (pc == 2) ? 2 : ((pc == 1 || pc == 3) ? 1 : 0);
            if (!nt) continue;
            uint32_t t_g = (uint32_t)c * 6u + (uint32_t)k;
            uint32_t row0;
            if (nt == 1) { row0 = r1; r1++; }
            else         { row0 = NF1 + 2u * r2; r2++; }
            for (int tri = 0; tri < nt; tri++) {
                uint32_t rr = row0 + (uint32_t)tri;
                float* f = out + (size_t)fbase + (size_t)rr * 3;
                float* u = out + (size_t)ubase + (size_t)rr * 3;
#pragma unroll
                for (int j = 0; j < 3; j++) {
                    int e = d_tt[ti][tri * 3 + j];
                    int c0 = d_six[k][d_eb[e][0]];
                    int c1 = d_six[k][d_eb[e][1]];
                    int bl = c0 & c1;
                    int rank = (c0 ^ c1) - 1;
                    int v0 = base + corner_off(bl);
                    uint32_t vid = (uint32_t)vloc[v0] + vsums[(v0 / N1) >> 1] +
                                   (uint32_t)__popc((uint32_t)mask[v0] & ((1u << rank) - 1u));
                    f[j] = (float)vid;
                }
                u[0] = (float)(4u * t_g);
                u[1] = (float)(4u * t_g + (uint32_t)tri + 1u);
                u[2] = (float)(4u * t_g + (uint32_t)tri + 2u);
            }
        }
    }
}

extern "C" void kernel_launch(void* const* d_in, const int* in_sizes, int n_in,
                              void* d_out, int out_size, void* d_ws, size_t ws_size,
                              hipStream_t stream) {
    const float* pos = (const float*)d_in[0];
    const float* sdf = (const float*)d_in[1];
    float* out = (float*)d_out;

    uint8_t* ws = (uint8_t*)d_ws;
    size_t off = 0;
    auto alloc = [&](size_t bytes) {
        void* p = ws + off;
        off = (off + bytes + 255) & ~(size_t)255;
        return p;
    };
    uint32_t* tot   = (uint32_t*)alloc(64);
    uint8_t*  mask  = (uint8_t*)alloc(NV3);
    uint16_t* vloc  = (uint16_t*)alloc((size_t)NV3 * 2);
    uint32_t* vsums = (uint32_t*)alloc((size_t)NBLK1 * 4);
    uint8_t*  cocc  = (uint8_t*)alloc(NCELL);
    uint32_t* cloc  = (uint32_t*)alloc((size_t)NCELL * 4);
    uint64_t* csums = (uint64_t*)alloc((size_t)NBLK1 * 8);

    hipLaunchKernelGGL(k_p1, dim3(NBLK1), dim3(256), 0, stream,
                       sdf, mask, vloc, vsums, cocc, cloc, csums);
    hipLaunchKernelGGL(k_sums2, dim3(1), dim3(256), 0, stream, vsums, csums, tot);
    hipLaunchKernelGGL(k_p2, dim3(P2BLOCKS), dim3(256), 0, stream,
                       sdf, pos, mask, vloc, vsums, cocc, cloc, csums, tot, out);
}

// Round 5
// 65.314 us; speedup vs baseline: 26.1557x; 1.4912x over previous
//
#include <hip/hip_runtime.h>
#include <stdint.h>

#define N1     97
#define N1SQ   9409
#define NV3    912673      // 97^3 lattice vertices
#define RES    96
#define NCELL  884736      // 96^3 cells
#define NCOLS  9409        // 97*97 z-columns
#define NBLK1  4705        // ceil(NCOLS/2): phase-1 blocks (2 columns each)
#define SEG    19          // NBLK1 <= 256*SEG
#define UVFLOATS 42467328  // 2304^2*8

#define VB2 3566           // ceil(NV3/256)
#define FB2 3456           // NCELL/256
#define NSPARSE (VB2 + FB2)                        // 7022
#define UVB2 10368                                 // uvs blocks (1024 float4 each)
#define P2BLOCKS (2 * NSPARSE + (UVB2 - NSPARSE))  // 17390

typedef float f4v __attribute__((ext_vector_type(4)));

__device__ __constant__ int d_tt[16][6] = {
    {-1,-1,-1,-1,-1,-1}, {1,0,2,-1,-1,-1}, {4,0,3,-1,-1,-1}, {1,4,2,1,3,4},
    {3,1,5,-1,-1,-1}, {2,3,0,2,5,3}, {1,4,0,1,5,4}, {4,2,5,-1,-1,-1},
    {4,5,2,-1,-1,-1}, {4,1,0,4,5,1}, {3,2,0,3,5,2}, {1,3,5,-1,-1,-1},
    {4,1,2,4,3,1}, {3,0,4,-1,-1,-1}, {2,0,1,-1,-1,-1}, {-1,-1,-1,-1,-1,-1}};
__device__ __constant__ int d_six[6][4] = {
    {0,5,1,7},{0,1,3,7},{0,3,2,7},{0,2,6,7},{0,6,4,7},{0,4,5,7}};
__device__ __constant__ int d_eb[6][2] = {{0,1},{0,2},{0,3},{1,2},{1,3},{2,3}};
__device__ __constant__ int d_diroff[7] = {1, 97, 98, 9409, 9410, 9506, 9507};

__device__ __forceinline__ int corner_off(int b) {
    return (b >> 2) * N1SQ + ((b >> 1) & 1) * N1 + (b & 1);
}

__device__ __forceinline__ float uvval(uint32_t p) {
    uint32_t cell = p >> 3;
    uint32_t k = p & 7u;
    uint32_t i = cell / 2304u;
    uint32_t j = cell - i * 2304u;
    uint32_t idx = (k & 1u) ? i : j;
    bool addpad = (k & 1u) ? (k >= 5u) : (k == 2u || k == 4u);
    return (float)idx * (1.0f / 2304.0f) + (addpad ? 0.9f / 2304.0f : 0.0f);
}

// Phase 1: 2 z-columns per block; coalesced loads; vertex mask + cell occ from
// the same 4 loads via LDS sign table; packed u64 wave scan (1 barrier).
__global__ __launch_bounds__(256) void k_p1(const float* __restrict__ sdf,
                                            uint8_t* __restrict__ mask,
                                            uint16_t* __restrict__ vloc,
                                            uint32_t* __restrict__ vsums,
                                            uint8_t* __restrict__ cocc,
                                            uint32_t* __restrict__ cloc,
                                            uint64_t* __restrict__ csums) {
    __shared__ uint8_t  sgn[2][128];
    __shared__ uint64_t wtc[4];
    int t = threadIdx.x;
    int lane = t & 63, wv = t >> 6;
    int bid = blockIdx.x;
    int half = t >> 7, z = t & 127;
    int col = bid * 2 + half;
    bool vcol = col < NCOLS;
    int x = 0, y = 0;
    if (vcol) { x = col / N1; y = col - x * N1; }
    bool bx = x < RES, by = y < RES, bz = z < RES;
    bool vact = vcol && (z < N1);
    int b00 = col * N1;
    float f00 = 0.f, f01 = 0.f, f10 = 0.f, f11 = 0.f;
    if (vact) {
        f00 = sdf[b00 + z];
        if (by) f01 = sdf[b00 + N1 + z];
        if (bx) f10 = sdf[b00 + N1SQ + z];
        if (bx && by) f11 = sdf[b00 + N1SQ + N1 + z];
    }
    uint32_t sb = (f00 >= 0.f ? 1u : 0u) | (f01 >= 0.f ? 2u : 0u) |
                  (f10 >= 0.f ? 4u : 0u) | (f11 >= 0.f ? 8u : 0u);
    sgn[half][z] = (uint8_t)sb;
    __syncthreads();
    uint32_t s1 = bz ? (uint32_t)sgn[half][z + 1] : 0u;

    uint32_t o0 = sb & 1u;
    uint32_t vm = 0;
    if (vact) {
        if (bz && ((s1 & 1u) != o0)) vm |= 1u;
        if (by && (((sb >> 1) & 1u) != o0)) vm |= 2u;
        if (by && bz && (((s1 >> 1) & 1u) != o0)) vm |= 4u;
        if (bx && (((sb >> 2) & 1u) != o0)) vm |= 8u;
        if (bx && bz && (((s1 >> 2) & 1u) != o0)) vm |= 16u;
        if (bx && by && (((sb >> 3) & 1u) != o0)) vm |= 32u;
        if (bx && by && bz && (((s1 >> 3) & 1u) != o0)) vm |= 64u;
    }
    uint32_t cnt = __popc(vm);
    bool cact = vact && bx && by && bz;
    uint32_t occ = 0, m1 = 0, m2 = 0;
    if (cact) {
        occ = (sb & 1u) | ((s1 & 1u) << 1) | (((sb >> 1) & 1u) << 2) | (((s1 >> 1) & 1u) << 3) |
              (((sb >> 2) & 1u) << 4) | (((s1 >> 2) & 1u) << 5) |
              (((sb >> 3) & 1u) << 6) | (((s1 >> 3) & 1u) << 7);
        if (occ != 0u && occ != 255u) {
#pragma unroll
            for (int k = 0; k < 6; k++) {
                int ti = ((occ >> d_six[k][0]) & 1) | (((occ >> d_six[k][1]) & 1) << 1) |
                         (((occ >> d_six[k][2]) & 1) << 2) | (((occ >> d_six[k][3]) & 1) << 3);
                int pc = __popc((uint32_t)ti);
                m1 += (pc == 1 || pc == 3) ? 1u : 0u;
                m2 += (pc == 2) ? 1u : 0u;
            }
        }
    }
    uint64_t val = (uint64_t)(cnt | (m1 << 16)) | ((uint64_t)m2 << 32);
    unsigned long long incl = val;
#pragma unroll
    for (int d = 1; d < 64; d <<= 1) {
        unsigned long long u = __shfl_up(incl, d, 64);
        if (lane >= d) incl += u;
    }
    if (lane == 63) wtc[wv] = incl;
    __syncthreads();
    uint64_t pre = 0;
#pragma unroll
    for (int w = 0; w < 4; w++)
        if (w < wv) pre += wtc[w];
    uint64_t excl = pre + (uint64_t)incl - val;
    uint64_t btot = wtc[0] + wtc[1] + wtc[2] + wtc[3];

    if (vact) {
        mask[b00 + z] = (uint8_t)vm;
        vloc[b00 + z] = (uint16_t)(excl & 0xffffu);
    }
    if (cact) {
        int c = (x * RES + y) * RES + z;
        cocc[c] = (uint8_t)occ;
        cloc[c] = (uint32_t)((excl >> 16) & 0xffffu) | ((uint32_t)((excl >> 32) & 0xffffu) << 16);
    }
    if (t == 0) {
        vsums[bid] = (uint32_t)(btot & 0xffffu);
        csums[bid] = ((btot >> 16) & 0xffffu) | (((btot >> 32) & 0xffffu) << 32);
    }
}

// Sums: one block, segmented scan of the block sums + totals/offsets.
__global__ __launch_bounds__(256) void k_sums2(uint32_t* __restrict__ vsums,
                                               uint64_t* __restrict__ csums,
                                               uint32_t* __restrict__ tot) {
    __shared__ uint32_t wtv[4];
    __shared__ uint64_t wtc[4];
    int t = threadIdx.x;
    int lane = t & 63, wv = t >> 6;
    uint32_t sv = 0; uint64_t sc = 0;
    int base = t * SEG;
#pragma unroll 1
    for (int j = 0; j < SEG; j++) {
        int idx = base + j;
        if (idx < NBLK1) { sv += vsums[idx]; sc += csums[idx]; }
    }
    uint32_t iv = sv; unsigned long long ic = sc;
#pragma unroll
    for (int d = 1; d < 64; d <<= 1) {
        uint32_t u1 = __shfl_up(iv, d, 64);
        unsigned long long u2 = __shfl_up(ic, d, 64);
        if (lane >= d) { iv += u1; ic += u2; }
    }
    if (lane == 63) { wtv[wv] = iv; wtc[wv] = ic; }
    __syncthreads();
    uint32_t pv = 0; uint64_t pc2 = 0;
#pragma unroll
    for (int w = 0; w < 4; w++)
        if (w < wv) { pv += wtv[w]; pc2 += wtc[w]; }
    uint32_t rv = pv + iv - sv;
    uint64_t rc = pc2 + (uint64_t)ic - sc;
#pragma unroll 1
    for (int j = 0; j < SEG; j++) {
        int idx = base + j;
        if (idx < NBLK1) {
            uint32_t a = vsums[idx]; uint64_t b = csums[idx];
            vsums[idx] = rv; csums[idx] = rc;
            rv += a; rc += b;
        }
    }
    if (t == 0) {
        uint32_t NV  = wtv[0] + wtv[1] + wtv[2] + wtv[3];
        uint64_t tc  = wtc[0] + wtc[1] + wtc[2] + wtc[3];
        uint32_t NF1 = (uint32_t)(tc & 0xffffffffu);
        uint32_t NF2 = (uint32_t)(tc >> 32);
        uint32_t NF  = NF1 + 2u * NF2;
        tot[0] = NV; tot[1] = NF1; tot[2] = NF2;
        tot[3] = NV * 6u;
        tot[4] = NV * 6u + NF * 3u;
        tot[5] = NV * 6u + NF * 3u + UVFLOATS;
    }
}

// Phase 2 fused: interleaved roles; uvs writes (BW-bound, plain float4) overlap
// wave-redistributed verts/faces emission (compact LDS worklists per wave).
__global__ __launch_bounds__(256) void k_p2(const float* __restrict__ sdf,
                                            const float* __restrict__ pos,
                                            const uint8_t* __restrict__ mask,
                                            const uint16_t* __restrict__ vloc,
                                            const uint32_t* __restrict__ vsums,
                                            const uint8_t* __restrict__ cocc,
                                            const uint32_t* __restrict__ cloc,
                                            const uint64_t* __restrict__ csums,
                                            const uint32_t* __restrict__ tot,
                                            float* __restrict__ out) {
    __shared__ uint2 ls[4][768];   // verts: <=448 used; faces: <=768
    int bid = blockIdx.x;
    int t = threadIdx.x;
    int lane = t & 63, wv = t >> 6;
    int sparse = -1, uvb = -1;
    if (bid < 2 * NSPARSE) {
        if (bid & 1) uvb = bid >> 1;
        else sparse = bid >> 1;
    } else {
        uvb = NSPARSE + (bid - 2 * NSPARSE);
    }

    if (uvb >= 0) {
        uint32_t tot4 = tot[4];
        uint32_t A = (tot4 + 3u) & ~3u;
        uint32_t end = tot4 + UVFLOATS;
        uint32_t nvec = (end - A) >> 2;
#pragma unroll
        for (int rr = 0; rr < 4; rr++) {
            uint32_t vi = (uint32_t)uvb * 1024u + (uint32_t)rr * 256u + (uint32_t)t;
            if (vi < nvec) {
                uint32_t e = A + vi * 4u;
                uint32_t p = e - tot4;
                f4v val;
                val.x = uvval(p);
                val.y = uvval(p + 1u);
                val.z = uvval(p + 2u);
                val.w = uvval(p + 3u);
                *(f4v*)(out + e) = val;
            }
        }
        if (uvb == 0 && t == 0) {
            for (uint32_t e = tot4; e < A; e++) out[e] = uvval(e - tot4);
            for (uint32_t e = A + nvec * 4u; e < end; e++) out[e] = uvval(e - tot4);
        }
        return;
    }

    if (sparse < VB2) {
        // ---- verts role: wave-compacted edge list ----
        int v = sparse * 256 + wv * 64 + lane;
        uint32_t m = (v < NV3) ? (uint32_t)mask[v] : 0u;
        uint32_t cnt = __popc(m);
        uint32_t incl = cnt;
#pragma unroll
        for (int d = 1; d < 64; d <<= 1) {
            uint32_t u = __shfl_up(incl, d, 64);
            if (lane >= d) incl += u;
        }
        uint32_t E = __shfl(incl, 63);
        if (E == 0) return;
        uint32_t slot = incl - cnt;
        if (cnt) {
            uint32_t gvid = (uint32_t)vloc[v] + vsums[(v / N1) >> 1];
#pragma unroll
            for (int d = 0; d < 7; d++) {
                if ((m >> d) & 1u) {
                    ls[wv][slot] = make_uint2((uint32_t)v, (gvid << 3) | (uint32_t)d);
                    gvid++; slot++;
                }
            }
        }
        for (uint32_t j = lane; j < E; j += 64) {
            uint2 e = ls[wv][j];
            uint32_t v0 = e.x;
            uint32_t dir = e.y & 7u;
            uint32_t vid = e.y >> 3;
            uint32_t b = v0 + (uint32_t)d_diroff[dir];
            float sa = sdf[v0];
            float sbv = sdf[b];
            float inv = 1.0f / (sa - sbv);
            float w0 = -sbv * inv;
            float w1 = sa * inv;
            const float2* pa2 = (const float2*)(pos + (size_t)v0 * 6);
            const float2* pb2 = (const float2*)(pos + (size_t)b * 6);
            float2* o2 = (float2*)(out + (size_t)vid * 6);
#pragma unroll
            for (int k = 0; k < 3; k++) {
                float2 a = pa2[k], bb = pb2[k];
                float2 o;
                o.x = a.x * w0 + bb.x * w1;
                o.y = a.y * w0 + bb.y * w1;
                o2[k] = o;
            }
        }
        return;
    }

    // ---- faces role: wave-compacted triangle list ----
    {
        int c = (sparse - VB2) * 256 + wv * 64 + lane;  // < NCELL always
        uint32_t occ = cocc[c];
        bool valid = (occ != 0u && occ != 255u);
        uint32_t NF1 = tot[1];
        // owner: enumerate triangles, count
        uint32_t tis = 0, nts = 0, cnt = 0;
        if (valid) {
#pragma unroll
            for (int k = 0; k < 6; k++) {
                int ti = ((occ >> d_six[k][0]) & 1) | (((occ >> d_six[k][1]) & 1) << 1) |
                         (((occ >> d_six[k][2]) & 1) << 2) | (((occ >> d_six[k][3]) & 1) << 3);
                int pc = __popc((uint32_t)ti);
                int nt = (pc == 2) ? 2 : ((pc == 1 || pc == 3) ? 1 : 0);
                tis |= (uint32_t)ti << (4 * k);
                nts |= (uint32_t)nt << (2 * k);
                cnt += (uint32_t)nt;
            }
        }
        uint32_t incl = cnt;
#pragma unroll
        for (int d = 1; d < 64; d <<= 1) {
            uint32_t u = __shfl_up(incl, d, 64);
            if (lane >= d) incl += u;
        }
        uint32_t E = __shfl(incl, 63);
        if (E == 0) return;
        uint32_t slot = incl - cnt;
        if (cnt) {
            uint32_t cl = cloc[c];
            uint64_t cs = csums[(((c / (RES * RES)) * N1) + ((c / RES) % RES)) >> 1];
            uint32_t r1 = (uint32_t)(cs & 0xffffffffu) + (cl & 0xffffu);
            uint32_t r2 = (uint32_t)(cs >> 32) + (cl >> 16);
#pragma unroll 1
            for (int k = 0; k < 6; k++) {
                uint32_t nt = (nts >> (2 * k)) & 3u;
                if (!nt) continue;
                uint32_t ti = (tis >> (4 * k)) & 15u;
                uint32_t row0;
                if (nt == 1) { row0 = r1; r1++; }
                else         { row0 = NF1 + 2u * r2; r2++; }
                for (uint32_t tri = 0; tri < nt; tri++) {
                    ls[wv][slot] = make_uint2((uint32_t)c,
                        ((row0 + tri) << 8) | (ti << 4) | ((uint32_t)k << 1) | tri);
                    slot++;
                }
            }
        }
        uint32_t fbase = tot[3];
        uint32_t ubase = tot[5];
        for (uint32_t j = lane; j < E; j += 64) {
            uint2 e = ls[wv][j];
            uint32_t cc = e.x;
            uint32_t tri = e.y & 1u;
            uint32_t k = (e.y >> 1) & 7u;
            uint32_t ti = (e.y >> 4) & 15u;
            uint32_t rr = e.y >> 8;
            uint32_t cx = cc / (RES * RES);
            uint32_t r0 = cc - cx * (RES * RES);
            uint32_t cy = r0 / RES;
            uint32_t cz = r0 - cy * RES;
            int base = (int)(cx * N1SQ + cy * N1 + cz);
            float* f = out + (size_t)fbase + (size_t)rr * 3;
            float* u = out + (size_t)ubase + (size_t)rr * 3;
#pragma unroll
            for (int jj = 0; jj < 3; jj++) {
                int ee = d_tt[ti][tri * 3 + jj];
                int c0 = d_six[k][d_eb[ee][0]];
                int c1 = d_six[k][d_eb[ee][1]];
                int bl = c0 & c1;
                int rank = (c0 ^ c1) - 1;
                int v0 = base + corner_off(bl);
                uint32_t vid = (uint32_t)vloc[v0] + vsums[(v0 / N1) >> 1] +
                               (uint32_t)__popc((uint32_t)mask[v0] & ((1u << rank) - 1u));
                f[jj] = (float)vid;
            }
            uint32_t t_g = cc * 6u + k;
            u[0] = (float)(4u * t_g);
            u[1] = (float)(4u * t_g + tri + 1u);
            u[2] = (float)(4u * t_g + tri + 2u);
        }
    }
}

extern "C" void kernel_launch(void* const* d_in, const int* in_sizes, int n_in,
                              void* d_out, int out_size, void* d_ws, size_t ws_size,
                              hipStream_t stream) {
    const float* pos = (const float*)d_in[0];
    const float* sdf = (const float*)d_in[1];
    float* out = (float*)d_out;

    uint8_t* ws = (uint8_t*)d_ws;
    size_t off = 0;
    auto alloc = [&](size_t bytes) {
        void* p = ws + off;
        off = (off + bytes + 255) & ~(size_t)255;
        return p;
    };
    uint32_t* tot   = (uint32_t*)alloc(64);
    uint8_t*  mask  = (uint8_t*)alloc(NV3);
    uint16_t* vloc  = (uint16_t*)alloc((size_t)NV3 * 2);
    uint32_t* vsums = (uint32_t*)alloc((size_t)NBLK1 * 4);
    uint8_t*  cocc  = (uint8_t*)alloc(NCELL);
    uint32_t* cloc  = (uint32_t*)alloc((size_t)NCELL * 4);
    uint64_t* csums = (uint64_t*)alloc((size_t)NBLK1 * 8);

    hipLaunchKernelGGL(k_p1, dim3(NBLK1), dim3(256), 0, stream,
                       sdf, mask, vloc, vsums, cocc, cloc, csums);
    hipLaunchKernelGGL(k_sums2, dim3(1), dim3(256), 0, stream, vsums, csums, tot);
    hipLaunchKernelGGL(k_p2, dim3(P2BLOCKS), dim3(256), 0, stream,
                       sdf, pos, mask, vloc, vsums, cocc, cloc, csums, tot, out);
}

// Round 6
// 56.462 us; speedup vs baseline: 30.2566x; 1.1568x over previous
//
#include <hip/hip_runtime.h>
#include <stdint.h>

#define N1     97
#define N1SQ   9409
#define NV3    912673      // 97^3 lattice vertices
#define RES    96
#define NCELL  884736      // 96^3 cells
#define NCOLS  9409        // 97*97 z-columns
#define COLS_PER_BLK 8
#define NBLK1  1177        // ceil(NCOLS/8): phase-1 blocks (8 columns each, 1024 thr)
#define SEG    2           // NBLK1 <= 1024*SEG
#define UVFLOATS 42467328  // 2304^2*8

#define VB2 3566           // ceil(NV3/256)
#define FB2 3456           // NCELL/256
#define NSPARSE (VB2 + FB2)                        // 7022
#define UVB2 10368                                 // uvs blocks (1024 float4 each)
#define P2BLOCKS (2 * NSPARSE + (UVB2 - NSPARSE))  // 17390

typedef float f4v __attribute__((ext_vector_type(4)));

__device__ __constant__ int d_tt[16][6] = {
    {-1,-1,-1,-1,-1,-1}, {1,0,2,-1,-1,-1}, {4,0,3,-1,-1,-1}, {1,4,2,1,3,4},
    {3,1,5,-1,-1,-1}, {2,3,0,2,5,3}, {1,4,0,1,5,4}, {4,2,5,-1,-1,-1},
    {4,5,2,-1,-1,-1}, {4,1,0,4,5,1}, {3,2,0,3,5,2}, {1,3,5,-1,-1,-1},
    {4,1,2,4,3,1}, {3,0,4,-1,-1,-1}, {2,0,1,-1,-1,-1}, {-1,-1,-1,-1,-1,-1}};
__device__ __constant__ int d_six[6][4] = {
    {0,5,1,7},{0,1,3,7},{0,3,2,7},{0,2,6,7},{0,6,4,7},{0,4,5,7}};
__device__ __constant__ int d_eb[6][2] = {{0,1},{0,2},{0,3},{1,2},{1,3},{2,3}};
__device__ __constant__ int d_diroff[7] = {1, 97, 98, 9409, 9410, 9506, 9507};

__device__ __forceinline__ int corner_off(int b) {
    return (b >> 2) * N1SQ + ((b >> 1) & 1) * N1 + (b & 1);
}

__device__ __forceinline__ float uvval(uint32_t p) {
    uint32_t cell = p >> 3;
    uint32_t k = p & 7u;
    uint32_t i = cell / 2304u;
    uint32_t j = cell - i * 2304u;
    uint32_t idx = (k & 1u) ? i : j;
    bool addpad = (k & 1u) ? (k >= 5u) : (k == 2u || k == 4u);
    return (float)idx * (1.0f / 2304.0f) + (addpad ? 0.9f / 2304.0f : 0.0f);
}

// Phase 1: 8 z-columns per 1024-thread block; coalesced loads; vertex mask +
// cell occ from the same 4 loads via LDS sign table; packed u64 two-level scan.
__global__ __launch_bounds__(1024) void k_p1(const float* __restrict__ sdf,
                                             uint8_t* __restrict__ mask,
                                             uint16_t* __restrict__ vloc,
                                             uint32_t* __restrict__ vsums,
                                             uint8_t* __restrict__ cocc,
                                             uint32_t* __restrict__ cloc,
                                             uint64_t* __restrict__ csums) {
    __shared__ uint8_t  sgn[COLS_PER_BLK][128];
    __shared__ uint64_t wtc[16];
    int t = threadIdx.x;
    int lane = t & 63, wv = t >> 6;
    int bid = blockIdx.x;
    int sub = t >> 7, z = t & 127;
    int col = bid * COLS_PER_BLK + sub;
    bool vcol = col < NCOLS;
    int x = 0, y = 0;
    if (vcol) { x = col / N1; y = col - x * N1; }
    bool bx = x < RES, by = y < RES, bz = z < RES;
    bool vact = vcol && (z < N1);
    int b00 = col * N1;
    float f00 = 0.f, f01 = 0.f, f10 = 0.f, f11 = 0.f;
    if (vact) {
        f00 = sdf[b00 + z];
        if (by) f01 = sdf[b00 + N1 + z];
        if (bx) f10 = sdf[b00 + N1SQ + z];
        if (bx && by) f11 = sdf[b00 + N1SQ + N1 + z];
    }
    uint32_t sb = (f00 >= 0.f ? 1u : 0u) | (f01 >= 0.f ? 2u : 0u) |
                  (f10 >= 0.f ? 4u : 0u) | (f11 >= 0.f ? 8u : 0u);
    sgn[sub][z] = (uint8_t)sb;
    __syncthreads();
    uint32_t s1 = bz ? (uint32_t)sgn[sub][z + 1] : 0u;

    uint32_t o0 = sb & 1u;
    uint32_t vm = 0;
    if (vact) {
        if (bz && ((s1 & 1u) != o0)) vm |= 1u;
        if (by && (((sb >> 1) & 1u) != o0)) vm |= 2u;
        if (by && bz && (((s1 >> 1) & 1u) != o0)) vm |= 4u;
        if (bx && (((sb >> 2) & 1u) != o0)) vm |= 8u;
        if (bx && bz && (((s1 >> 2) & 1u) != o0)) vm |= 16u;
        if (bx && by && (((sb >> 3) & 1u) != o0)) vm |= 32u;
        if (bx && by && bz && (((s1 >> 3) & 1u) != o0)) vm |= 64u;
    }
    uint32_t cnt = __popc(vm);
    bool cact = vact && bx && by && bz;
    uint32_t occ = 0, m1 = 0, m2 = 0;
    if (cact) {
        occ = (sb & 1u) | ((s1 & 1u) << 1) | (((sb >> 1) & 1u) << 2) | (((s1 >> 1) & 1u) << 3) |
              (((sb >> 2) & 1u) << 4) | (((s1 >> 2) & 1u) << 5) |
              (((sb >> 3) & 1u) << 6) | (((s1 >> 3) & 1u) << 7);
        if (occ != 0u && occ != 255u) {
#pragma unroll
            for (int k = 0; k < 6; k++) {
                int ti = ((occ >> d_six[k][0]) & 1) | (((occ >> d_six[k][1]) & 1) << 1) |
                         (((occ >> d_six[k][2]) & 1) << 2) | (((occ >> d_six[k][3]) & 1) << 3);
                int pc = __popc((uint32_t)ti);
                m1 += (pc == 1 || pc == 3) ? 1u : 0u;
                m2 += (pc == 2) ? 1u : 0u;
            }
        }
    }
    // packed u64 scan: cnt[0:16) | m1[16:32) | m2[32:..)
    uint64_t val = (uint64_t)(cnt | (m1 << 16)) | ((uint64_t)m2 << 32);
    unsigned long long incl = val;
#pragma unroll
    for (int d = 1; d < 64; d <<= 1) {
        unsigned long long u = __shfl_up(incl, d, 64);
        if (lane >= d) incl += u;
    }
    if (lane == 63) wtc[wv] = incl;
    __syncthreads();
    uint64_t pre = 0;
#pragma unroll
    for (int w = 0; w < 16; w++)
        if (w < wv) pre += wtc[w];
    uint64_t excl = pre + (uint64_t)incl - val;

    if (vact) {
        mask[b00 + z] = (uint8_t)vm;
        vloc[b00 + z] = (uint16_t)(excl & 0xffffu);
    }
    if (cact) {
        int c = (x * RES + y) * RES + z;
        cocc[c] = (uint8_t)occ;
        cloc[c] = (uint32_t)((excl >> 16) & 0xffffu) | ((uint32_t)((excl >> 32) & 0xffffu) << 16);
    }
    if (t == 0) {
        uint64_t btot = 0;
#pragma unroll
        for (int w = 0; w < 16; w++) btot += wtc[w];
        vsums[bid] = (uint32_t)(btot & 0xffffu);
        csums[bid] = ((btot >> 16) & 0xffffu) | (((btot >> 32) & 0xffffu) << 32);
    }
}

// Sums: one 1024-thread block, SEG=2 segmented two-level scan + totals/offsets.
__global__ __launch_bounds__(1024) void k_sums2(uint32_t* __restrict__ vsums,
                                                uint64_t* __restrict__ csums,
                                                uint32_t* __restrict__ tot) {
    __shared__ uint32_t wtv[16];
    __shared__ uint64_t wtc[16];
    int t = threadIdx.x;
    int lane = t & 63, wv = t >> 6;
    uint32_t sv = 0; uint64_t sc = 0;
    int base = t * SEG;
#pragma unroll
    for (int j = 0; j < SEG; j++) {
        int idx = base + j;
        if (idx < NBLK1) { sv += vsums[idx]; sc += csums[idx]; }
    }
    uint32_t iv = sv; unsigned long long ic = sc;
#pragma unroll
    for (int d = 1; d < 64; d <<= 1) {
        uint32_t u1 = __shfl_up(iv, d, 64);
        unsigned long long u2 = __shfl_up(ic, d, 64);
        if (lane >= d) { iv += u1; ic += u2; }
    }
    if (lane == 63) { wtv[wv] = iv; wtc[wv] = ic; }
    __syncthreads();
    uint32_t pv = 0; uint64_t pc2 = 0;
#pragma unroll
    for (int w = 0; w < 16; w++)
        if (w < wv) { pv += wtv[w]; pc2 += wtc[w]; }
    uint32_t rv = pv + iv - sv;
    uint64_t rc = pc2 + (uint64_t)ic - sc;
#pragma unroll
    for (int j = 0; j < SEG; j++) {
        int idx = base + j;
        if (idx < NBLK1) {
            uint32_t a = vsums[idx]; uint64_t b = csums[idx];
            vsums[idx] = rv; csums[idx] = rc;
            rv += a; rc += b;
        }
    }
    if (t == 0) {
        uint32_t NV = 0; uint64_t tc = 0;
#pragma unroll
        for (int w = 0; w < 16; w++) { NV += wtv[w]; tc += wtc[w]; }
        uint32_t NF1 = (uint32_t)(tc & 0xffffffffu);
        uint32_t NF2 = (uint32_t)(tc >> 32);
        uint32_t NF  = NF1 + 2u * NF2;
        tot[0] = NV; tot[1] = NF1; tot[2] = NF2;
        tot[3] = NV * 6u;
        tot[4] = NV * 6u + NF * 3u;
        tot[5] = NV * 6u + NF * 3u + UVFLOATS;
    }
}

// Phase 2 fused: interleaved roles; uvs writes (BW-bound, plain float4) overlap
// wave-redistributed verts/faces emission (compact LDS worklists per wave).
__global__ __launch_bounds__(256) void k_p2(const float* __restrict__ sdf,
                                            const float* __restrict__ pos,
                                            const uint8_t* __restrict__ mask,
                                            const uint16_t* __restrict__ vloc,
                                            const uint32_t* __restrict__ vsums,
                                            const uint8_t* __restrict__ cocc,
                                            const uint32_t* __restrict__ cloc,
                                            const uint64_t* __restrict__ csums,
                                            const uint32_t* __restrict__ tot,
                                            float* __restrict__ out) {
    __shared__ uint2 ls[4][768];   // verts: <=448 used; faces: <=768
    int bid = blockIdx.x;
    int t = threadIdx.x;
    int lane = t & 63, wv = t >> 6;
    int sparse = -1, uvb = -1;
    if (bid < 2 * NSPARSE) {
        if (bid & 1) uvb = bid >> 1;
        else sparse = bid >> 1;
    } else {
        uvb = NSPARSE + (bid - 2 * NSPARSE);
    }

    if (uvb >= 0) {
        uint32_t tot4 = tot[4];
        uint32_t A = (tot4 + 3u) & ~3u;
        uint32_t end = tot4 + UVFLOATS;
        uint32_t nvec = (end - A) >> 2;
#pragma unroll
        for (int rr = 0; rr < 4; rr++) {
            uint32_t vi = (uint32_t)uvb * 1024u + (uint32_t)rr * 256u + (uint32_t)t;
            if (vi < nvec) {
                uint32_t e = A + vi * 4u;
                uint32_t p = e - tot4;
                f4v val;
                val.x = uvval(p);
                val.y = uvval(p + 1u);
                val.z = uvval(p + 2u);
                val.w = uvval(p + 3u);
                *(f4v*)(out + e) = val;
            }
        }
        if (uvb == 0 && t == 0) {
            for (uint32_t e = tot4; e < A; e++) out[e] = uvval(e - tot4);
            for (uint32_t e = A + nvec * 4u; e < end; e++) out[e] = uvval(e - tot4);
        }
        return;
    }

    if (sparse < VB2) {
        // ---- verts role: wave-compacted edge list ----
        int v = sparse * 256 + wv * 64 + lane;
        uint32_t m = (v < NV3) ? (uint32_t)mask[v] : 0u;
        uint32_t cnt = __popc(m);
        uint32_t incl = cnt;
#pragma unroll
        for (int d = 1; d < 64; d <<= 1) {
            uint32_t u = __shfl_up(incl, d, 64);
            if (lane >= d) incl += u;
        }
        uint32_t E = __shfl(incl, 63);
        if (E == 0) return;
        uint32_t slot = incl - cnt;
        if (cnt) {
            uint32_t gvid = (uint32_t)vloc[v] + vsums[(v / N1) >> 3];
#pragma unroll
            for (int d = 0; d < 7; d++) {
                if ((m >> d) & 1u) {
                    ls[wv][slot] = make_uint2((uint32_t)v, (gvid << 3) | (uint32_t)d);
                    gvid++; slot++;
                }
            }
        }
        for (uint32_t j = lane; j < E; j += 64) {
            uint2 e = ls[wv][j];
            uint32_t v0 = e.x;
            uint32_t dir = e.y & 7u;
            uint32_t vid = e.y >> 3;
            uint32_t b = v0 + (uint32_t)d_diroff[dir];
            float sa = sdf[v0];
            float sbv = sdf[b];
            float inv = 1.0f / (sa - sbv);
            float w0 = -sbv * inv;
            float w1 = sa * inv;
            const float2* pa2 = (const float2*)(pos + (size_t)v0 * 6);
            const float2* pb2 = (const float2*)(pos + (size_t)b * 6);
            float2* o2 = (float2*)(out + (size_t)vid * 6);
#pragma unroll
            for (int k = 0; k < 3; k++) {
                float2 a = pa2[k], bb = pb2[k];
                float2 o;
                o.x = a.x * w0 + bb.x * w1;
                o.y = a.y * w0 + bb.y * w1;
                o2[k] = o;
            }
        }
        return;
    }

    // ---- faces role: wave-compacted triangle list ----
    {
        int c = (sparse - VB2) * 256 + wv * 64 + lane;  // < NCELL always
        uint32_t occ = cocc[c];
        bool valid = (occ != 0u && occ != 255u);
        uint32_t NF1 = tot[1];
        uint32_t tis = 0, nts = 0, cnt = 0;
        if (valid) {
#pragma unroll
            for (int k = 0; k < 6; k++) {
                int ti = ((occ >> d_six[k][0]) & 1) | (((occ >> d_six[k][1]) & 1) << 1) |
                         (((occ >> d_six[k][2]) & 1) << 2) | (((occ >> d_six[k][3]) & 1) << 3);
                int pc = __popc((uint32_t)ti);
                int nt = (pc == 2) ? 2 : ((pc == 1 || pc == 3) ? 1 : 0);
                tis |= (uint32_t)ti << (4 * k);
                nts |= (uint32_t)nt << (2 * k);
                cnt += (uint32_t)nt;
            }
        }
        uint32_t incl = cnt;
#pragma unroll
        for (int d = 1; d < 64; d <<= 1) {
            uint32_t u = __shfl_up(incl, d, 64);
            if (lane >= d) incl += u;
        }
        uint32_t E = __shfl(incl, 63);
        if (E == 0) return;
        uint32_t slot = incl - cnt;
        if (cnt) {
            uint32_t cl = cloc[c];
            uint64_t cs = csums[(((c / (RES * RES)) * N1) + ((c / RES) % RES)) >> 3];
            uint32_t r1 = (uint32_t)(cs & 0xffffffffu) + (cl & 0xffffu);
            uint32_t r2 = (uint32_t)(cs >> 32) + (cl >> 16);
#pragma unroll 1
            for (int k = 0; k < 6; k++) {
                uint32_t nt = (nts >> (2 * k)) & 3u;
                if (!nt) continue;
                uint32_t ti = (tis >> (4 * k)) & 15u;
                uint32_t row0;
                if (nt == 1) { row0 = r1; r1++; }
                else         { row0 = NF1 + 2u * r2; r2++; }
                for (uint32_t tri = 0; tri < nt; tri++) {
                    ls[wv][slot] = make_uint2((uint32_t)c,
                        ((row0 + tri) << 8) | (ti << 4) | ((uint32_t)k << 1) | tri);
                    slot++;
                }
            }
        }
        uint32_t fbase = tot[3];
        uint32_t ubase = tot[5];
        for (uint32_t j = lane; j < E; j += 64) {
            uint2 e = ls[wv][j];
            uint32_t cc = e.x;
            uint32_t tri = e.y & 1u;
            uint32_t k = (e.y >> 1) & 7u;
            uint32_t ti = (e.y >> 4) & 15u;
            uint32_t rr = e.y >> 8;
            uint32_t cx = cc / (RES * RES);
            uint32_t r0 = cc - cx * (RES * RES);
            uint32_t cy = r0 / RES;
            uint32_t cz = r0 - cy * RES;
            int base = (int)(cx * N1SQ + cy * N1 + cz);
            float* f = out + (size_t)fbase + (size_t)rr * 3;
            float* u = out + (size_t)ubase + (size_t)rr * 3;
#pragma unroll
            for (int jj = 0; jj < 3; jj++) {
                int ee = d_tt[ti][tri * 3 + jj];
                int c0 = d_six[k][d_eb[ee][0]];
                int c1 = d_six[k][d_eb[ee][1]];
                int bl = c0 & c1;
                int rank = (c0 ^ c1) - 1;
                int v0 = base + corner_off(bl);
                uint32_t vid = (uint32_t)vloc[v0] + vsums[(v0 / N1) >> 3] +
                               (uint32_t)__popc((uint32_t)mask[v0] & ((1u << rank) - 1u));
                f[jj] = (float)vid;
            }
            uint32_t t_g = cc * 6u + k;
            u[0] = (float)(4u * t_g);
            u[1] = (float)(4u * t_g + tri + 1u);
            u[2] = (float)(4u * t_g + tri + 2u);
        }
    }
}

extern "C" void kernel_launch(void* const* d_in, const int* in_sizes, int n_in,
                              void* d_out, int out_size, void* d_ws, size_t ws_size,
                              hipStream_t stream) {
    const float* pos = (const float*)d_in[0];
    const float* sdf = (const float*)d_in[1];
    float* out = (float*)d_out;

    uint8_t* ws = (uint8_t*)d_ws;
    size_t off = 0;
    auto alloc = [&](size_t bytes) {
        void* p = ws + off;
        off = (off + bytes + 255) & ~(size_t)255;
        return p;
    };
    uint32_t* tot   = (uint32_t*)alloc(64);
    uint8_t*  mask  = (uint8_t*)alloc(NV3);
    uint16_t* vloc  = (uint16_t*)alloc((size_t)NV3 * 2);
    uint32_t* vsums = (uint32_t*)alloc((size_t)NBLK1 * 4);
    uint8_t*  cocc  = (uint8_t*)alloc(NCELL);
    uint32_t* cloc  = (uint32_t*)alloc((size_t)NCELL * 4);
    uint64_t* csums = (uint64_t*)alloc((size_t)NBLK1 * 8);

    hipLaunchKernelGGL(k_p1, dim3(NBLK1), dim3(1024), 0, stream,
                       sdf, mask, vloc, vsums, cocc, cloc, csums);
    hipLaunchKernelGGL(k_sums2, dim3(1), dim3(1024), 0, stream, vsums, csums, tot);
    hipLaunchKernelGGL(k_p2, dim3(P2BLOCKS), dim3(256), 0, stream,
                       sdf, pos, mask, vloc, vsums, cocc, cloc, csums, tot, out);
}